// Round 2
// baseline (113296.753 us; speedup 1.0000x reference)
//
#include <hip/hip_runtime.h>
#include <cstdint>
#include <cstddef>
#include <math.h>

// Exact Viterbi decode: N=512 states, T=8192, M=50257 tokens.
// The reference path must be matched bit-exactly (any argmax flip fails the
// absmax check), which pins the fp32 rounding sequence: v is computed
// sequentially by ONE workgroup, with an exactness-preserving row-pruning
// (monotonicity of IEEE fp32 add) to cut the 512x512 scan per step.

#define NT 512
#define TT 8192
#define MT 50257
#define DELTA1 0.125f

#define BT_L 32                  // backtrace segment length
#define BT_S (TT / BT_L)         // 256 segments

// ---- workspace layout (bytes) ---- (total == round-1's 26484736, known to fit)
#define WS_LOGPI   0u            // 512 f32
#define WS_VLAST   2048u         // 512 f32
#define WS_BOUND   4096u         // 257 i32
#define WS_ROWMAX  5632u         // 512 f32
#define WS_MAPS    8192u         // 256*512 u16 = 262144
#define WS_LA      270336u       // 512*512 f32 = 1048576 (row-major logA)
#define WS_EMIS    1318912u      // 8192*512 f32 = 16777216
#define WS_BP      18096128u     // 8192*512 u16 = 8388608
#define WS_NEED    26484736u

// Correctly-rounded fp32 logs via fp64 (matches np.log to CR; 1-ulp device
// logf vs numpy would risk O(1) path flips at large-|v| rounding boundaries).
__global__ void prep_logs(const float* __restrict__ A, const float* __restrict__ Pi,
                          float* __restrict__ lA, float* __restrict__ logPi) {
    int idx = blockIdx.x * blockDim.x + threadIdx.x;
    if (idx < NT * NT) {
        lA[idx] = (float)log((double)A[idx]);
    } else if (idx < NT * NT + NT) {
        int j = idx - NT * NT;
        logPi[j] = (float)log((double)Pi[j]);
    }
}

__global__ void prep_rowmax(const float* __restrict__ lA, float* __restrict__ rowmax) {
    __shared__ float s[4];
    int i = blockIdx.x;
    int t = threadIdx.x;                    // 256 threads
    float m = fmaxf(lA[i * NT + t], lA[i * NT + t + 256]);
    for (int k = 32; k >= 1; k >>= 1) m = fmaxf(m, __shfl_xor(m, k, 64));
    if ((t & 63) == 0) s[t >> 6] = m;
    __syncthreads();
    if (t == 0) {
        float r = fmaxf(fmaxf(s[0], s[1]), fmaxf(s[2], s[3]));
        rowmax[i] = r;                      // exact max of exact fp32 values
    }
}

__global__ void prep_emis(const float* __restrict__ B, const int* __restrict__ tok,
                          float* __restrict__ emis) {
    int idx = blockIdx.x * blockDim.x + threadIdx.x;   // t*512 + j
    if (idx >= TT * NT) return;
    int t = idx >> 9;
    int j = idx & (NT - 1);
    int tk = tok[t];
    float e;
    if (tk < 0) e = (float)log((double)(1.0f / 512.0f));
    else        e = (float)log((double)B[(size_t)j * MT + tk]);
    emis[idx] = e;
}

// Single-workgroup exact forward. 1024 threads: thread = (h = tid>>9, j = tid&511).
// Per step: c_i = fl(v_i + rowmax_i) upper-bounds row i (fl is monotone);
// T = min_j max_{i in L1} fl(v_i + a_ij) is an achieved lower bound; rows with
// c_i < T are strictly below every column max => safe to skip (ties kept by >=).
__launch_bounds__(1024, 1)
__global__ void viterbi_fwd_exact(const float* __restrict__ lA,
                                  const float* __restrict__ rowmax,
                                  const float* __restrict__ emis,
                                  const float* __restrict__ logPi,
                                  unsigned short* __restrict__ bp,
                                  float* __restrict__ vlast) {
    __shared__ float vL[NT];        // exact v_{t-1}
    __shared__ float vS[NT];        // compacted survivor v values
    __shared__ int   Sl[NT];        // compacted survivor indices (ascending)
    __shared__ float pm[2][NT];     // h-partial max values
    __shared__ int   pb[2][NT];     // h-partial argmax indices
    __shared__ float red[16];
    __shared__ int   redi[16];
    __shared__ float Msh, Tsh;

    const int tid  = threadIdx.x;
    const int j    = tid & (NT - 1);
    const int h    = tid >> 9;
    const int lane = tid & 63;
    const int wave = tid >> 6;      // h==0 => waves 0..7

    if (h == 0) vL[j] = logPi[j] + emis[j];   // exact v0
    __syncthreads();

    const float* __restrict__ lAj = lA + j;

    for (int t = 1; t < TT; ++t) {
        float e = emis[(size_t)t * NT + j];   // prefetch; used at step end

        // (1) c_i (register-resident for h==0 threads; i == j == tid)
        float c = 0.0f;
        if (h == 0) c = vL[j] + rowmax[j];

        // (2) M = max_i c_i
        if (h == 0) {
            float m = c;
            for (int k = 32; k >= 1; k >>= 1) m = fmaxf(m, __shfl_xor(m, k, 64));
            if (lane == 0) red[wave] = m;
        }
        __syncthreads();
        if (tid == 0) {
            float m = red[0];
            for (int w = 1; w < 8; ++w) m = fmaxf(m, red[w]);
            Msh = m;
        }
        __syncthreads();
        const float M = Msh;

        // (3) compact L1 = {i : c_i >= M - DELTA1} into Sl/vS (ascending i)
        if (h == 0) {
            bool pred = (c >= M - DELTA1);
            unsigned long long mk = __ballot(pred);
            if (lane == 0) redi[wave] = __popcll(mk);
        }
        __syncthreads();
        if (tid == 0) {
            int acc = 0;
            for (int w = 0; w < 8; ++w) { int x = redi[w]; redi[w] = acc; acc += x; }
            redi[8] = acc;
        }
        __syncthreads();
        int nL1 = redi[8];
        if (h == 0) {
            bool pred = (c >= M - DELTA1);
            unsigned long long mk = __ballot(pred);
            int pos = redi[wave] + __popcll(mk & ((1ull << lane) - 1ull));
            if (pred) { Sl[pos] = j; vS[pos] = vL[j]; }
        }
        __syncthreads();

        // (3b) lb pass over L1 rows (values only; achieved candidates)
        float lbm = -3.402823466e38f;
        for (int s = h; s < nL1; s += 2) {
            int i0   = Sl[s];
            float vi = vS[s];
            float a  = lAj[(size_t)i0 * NT];
            lbm = fmaxf(lbm, vi + a);
        }
        pm[h][j] = lbm;
        __syncthreads();

        // (4) T = min_j lb_j
        if (h == 0) {
            float mn = fmaxf(pm[0][j], pm[1][j]);
            for (int k = 32; k >= 1; k >>= 1) mn = fminf(mn, __shfl_xor(mn, k, 64));
            if (lane == 0) red[wave] = mn;
        }
        __syncthreads();
        if (tid == 0) {
            float mn = red[0];
            for (int w = 1; w < 8; ++w) mn = fminf(mn, red[w]);
            Tsh = mn;
        }
        __syncthreads();
        const float T = Tsh;

        // (5) compact survivors S = {i : c_i >= T} (>= keeps first-index ties)
        if (h == 0) {
            bool pred = (c >= T);
            unsigned long long mk = __ballot(pred);
            if (lane == 0) redi[wave] = __popcll(mk);
        }
        __syncthreads();
        if (tid == 0) {
            int acc = 0;
            for (int w = 0; w < 8; ++w) { int x = redi[w]; redi[w] = acc; acc += x; }
            redi[8] = acc;
        }
        __syncthreads();
        int scnt = redi[8];
        if (h == 0) {
            bool pred = (c >= T);
            unsigned long long mk = __ballot(pred);
            int pos = redi[wave] + __popcll(mk & ((1ull << lane) - 1ull));
            if (pred) { Sl[pos] = j; vS[pos] = vL[j]; }
        }
        __syncthreads();

        // (6) main pass: exact max + first-index argmax over survivors
        float m = -3.402823466e38f; int b = 0;
        for (int s = h; s < scnt; s += 2) {
            int i0   = Sl[s];
            float vi = vS[s];
            float a  = lAj[(size_t)i0 * NT];
            float sc = vi + a;                 // single-rounded fp32 add (== ref)
            if (sc > m) { m = sc; b = i0; }    // ascending i => first-index ties
        }
        pm[h][j] = m; pb[h][j] = b;
        __syncthreads();
        if (h == 0) {
            float m0 = pm[0][j]; int b0 = pb[0][j];
            float m1 = pm[1][j]; int b1 = pb[1][j];
            float mm; int bb;
            if (m1 > m0 || (m1 == m0 && b1 < b0)) { mm = m1; bb = b1; }
            else                                  { mm = m0; bb = b0; }
            float vn = mm + e;                 // single-rounded (== ref)
            bp[(size_t)t * NT + j] = (unsigned short)bb;
            vL[j] = vn;                        // all reads of vL are behind barriers
            if (t == TT - 1) vlast[j] = vn;
        }
        __syncthreads();
    }
}

// ---- backtrace: per-segment map composition (exact given bp, vlast) ----
__launch_bounds__(NT, 1)
__global__ void bt_maps(const unsigned short* __restrict__ bp,
                        unsigned short* __restrict__ maps) {
    __shared__ unsigned short bps[BT_L * NT];   // 32 KB
    const int s = blockIdx.x;
    const int tlo = BT_L * s + 1;
    int thi = BT_L * (s + 1); if (thi > TT - 1) thi = TT - 1;
    const int nt = thi - tlo + 1;
    for (int k = threadIdx.x; k < nt * NT; k += NT)
        bps[k] = bp[(size_t)tlo * NT + k];
    __syncthreads();
    int cur = threadIdx.x;                      // state at t = thi
    for (int r = nt - 1; r >= 0; --r) cur = bps[r * NT + cur];
    maps[s * NT + threadIdx.x] = (unsigned short)cur;  // state at t = 32*s
}

__launch_bounds__(NT, 1)
__global__ void bt_bound(const float* __restrict__ vlast,
                         const unsigned short* __restrict__ maps,
                         int* __restrict__ bound) {
    __shared__ float sv[NT];
    __shared__ int   si[NT];
    int j = threadIdx.x;
    sv[j] = vlast[j]; si[j] = j;
    __syncthreads();
    for (int off = NT / 2; off > 0; off >>= 1) {
        if (j < off) {
            float v2 = sv[j + off]; int i2 = si[j + off];
            if (v2 > sv[j] || (v2 == sv[j] && i2 < si[j])) { sv[j] = v2; si[j] = i2; }
        }
        __syncthreads();
    }
    if (j == 0) {
        int cur = si[0];
        bound[BT_S] = cur;                      // state at t = 8191
        for (int s = BT_S - 1; s >= 0; --s) {
            cur = maps[s * NT + cur];
            bound[s] = cur;                     // state at t = 32*s
        }
    }
}

__launch_bounds__(NT, 1)
__global__ void bt_path(const unsigned short* __restrict__ bp,
                        const int* __restrict__ bound,
                        int* __restrict__ path) {
    __shared__ unsigned short bps[BT_L * NT];
    const int s = blockIdx.x;
    const int tlo = BT_L * s + 1;
    int thi = BT_L * (s + 1); if (thi > TT - 1) thi = TT - 1;
    const int nt = thi - tlo + 1;
    for (int k = threadIdx.x; k < nt * NT; k += NT)
        bps[k] = bp[(size_t)tlo * NT + k];
    __syncthreads();
    if (threadIdx.x == 0) {
        int cur = bound[s + 1];
        if (s == BT_S - 1) path[TT - 1] = cur;
        for (int r = nt - 1; r >= 0; --r) {
            cur = bps[r * NT + cur];
            path[tlo - 1 + r] = cur;            // path[32s .. thi-1]
        }
    }
}

extern "C" void kernel_launch(void* const* d_in, const int* in_sizes, int n_in,
                              void* d_out, int out_size, void* d_ws, size_t ws_size,
                              hipStream_t stream) {
    const int*   tok = (const int*)d_in[0];
    const float* A   = (const float*)d_in[1];
    const float* B   = (const float*)d_in[2];
    const float* Pi  = (const float*)d_in[3];
    int* path = (int*)d_out;
    char* ws = (char*)d_ws;
    if (ws_size < (size_t)WS_NEED) return;

    float* logPi          = (float*)(ws + WS_LOGPI);
    float* vlast          = (float*)(ws + WS_VLAST);
    int*   bound          = (int*)(ws + WS_BOUND);
    float* rowmax         = (float*)(ws + WS_ROWMAX);
    unsigned short* maps  = (unsigned short*)(ws + WS_MAPS);
    float* lA             = (float*)(ws + WS_LA);
    float* emis           = (float*)(ws + WS_EMIS);
    unsigned short* bpp   = (unsigned short*)(ws + WS_BP);

    prep_logs  <<<(NT * NT + NT + 255) / 256, 256, 0, stream>>>(A, Pi, lA, logPi);
    prep_emis  <<<(TT * NT) / 256,            256, 0, stream>>>(B, tok, emis);
    prep_rowmax<<<NT, 256, 0, stream>>>(lA, rowmax);
    viterbi_fwd_exact<<<1, 1024, 0, stream>>>(lA, rowmax, emis, logPi, bpp, vlast);
    bt_maps  <<<BT_S, NT, 0, stream>>>(bpp, maps);
    bt_bound <<<1,    NT, 0, stream>>>(vlast, maps, bound);
    bt_path  <<<BT_S, NT, 0, stream>>>(bpp, bound, path);
}